// Round 6
// baseline (1282.896 us; speedup 1.0000x reference)
//
#include <hip/hip_runtime.h>

#define B_ 4
#define L_ 512
#define D_ 1024
#define E_ 16
#define K_ 4
#define F_ 4096
#define NTOK (B_*L_)      // 2048
#define NPAIR (NTOK*K_)   // 8192

typedef float f32x4 __attribute__((ext_vector_type(4)));
typedef __bf16 bf16x8 __attribute__((ext_vector_type(8)));

__device__ inline unsigned int pack2(float a, float b) {
    unsigned short ua = __builtin_bit_cast(unsigned short, (__bf16)a);
    unsigned short ub = __builtin_bit_cast(unsigned short, (__bf16)b);
    return (unsigned int)ua | ((unsigned int)ub << 16);
}

#define GLOAD16(g, l) __builtin_amdgcn_global_load_lds( \
    (const __attribute__((address_space(1))) void*)(g), \
    (__attribute__((address_space(3))) void*)(l), 16, 0, 0)

// bijective XCD-chunking: dispatch order round-robins XCDs; this makes each
// XCD own a CONTIGUOUS logical-id range (nwg must be a multiple of 8).
__device__ inline int xcdmap(int orig, int nwg) {
    int q = nwg >> 3;
    return (orig & 7) * q + (orig >> 3);
}

// ---------------- fp32 -> bf16 bulk convert (16 elems/thread) ----------------
__global__ __launch_bounds__(256) void cvt_kernel(const float* __restrict__ src,
                                                  unsigned short* __restrict__ dst)
{
    size_t i = ((size_t)blockIdx.x * 256 + threadIdx.x) * 16;
    const float4* s = reinterpret_cast<const float4*>(src + i);
    float4 v0 = s[0], v1 = s[1], v2 = s[2], v3 = s[3];
    uint4 p0 = { pack2(v0.x,v0.y), pack2(v0.z,v0.w), pack2(v1.x,v1.y), pack2(v1.z,v1.w) };
    uint4 p1 = { pack2(v2.x,v2.y), pack2(v2.z,v2.w), pack2(v3.x,v3.y), pack2(v3.z,v3.w) };
    uint4* d = reinterpret_cast<uint4*>(dst + i);
    d[0] = p0; d[1] = p1;
}

// ---------------- Router ----------------
__global__ __launch_bounds__(256) void router_kernel(
    const float* __restrict__ x, const float* __restrict__ keys,
    const float* __restrict__ rw, const float* __restrict__ rb,
    int* __restrict__ topi, float* __restrict__ topw, int* __restrict__ counts)
{
    int t = blockIdx.x;
    int tid = threadIdx.x;
    if (blockIdx.x == 0 && tid < E_) counts[tid] = 0;

    __shared__ float xs[D_];
    const float* xrow = x + (size_t)t * D_;
    for (int i = tid; i < D_; i += 256) xs[i] = xrow[i];
    __syncthreads();

    int e    = tid >> 4;
    int lane = tid & 15;
    const float* krow = keys + e * D_;
    const float* rrow = rw   + e * D_;
    double dist2 = 0.0, dot = 0.0;
    for (int d = lane; d < D_; d += 16) {
        float xv = xs[d];
        float df = xv - krow[d];
        dist2 += (double)df * df;
        dot   += (double)xv * rrow[d];
    }
    #pragma unroll
    for (int m = 8; m >= 1; m >>= 1) {
        dist2 += __shfl_xor(dist2, m);
        dot   += __shfl_xor(dot, m);
    }
    __shared__ float lg[E_];
    if (lane == 0) lg[e] = (float)(-dist2 + dot) + rb[e];
    __syncthreads();

    if (tid == 0) {
        float v[E_];
        #pragma unroll
        for (int i = 0; i < E_; i++) v[i] = lg[i];
        int   idx[K_]; float val[K_];
        #pragma unroll
        for (int k = 0; k < K_; k++) {
            int bi = 0; float bv = -1e30f;
            #pragma unroll
            for (int i = 0; i < E_; i++) if (v[i] > bv) { bv = v[i]; bi = i; }
            idx[k] = bi; val[k] = bv; v[bi] = -1e30f;
        }
        float mx = val[0], s = 0.f, w[K_];
        #pragma unroll
        for (int k = 0; k < K_; k++) { w[k] = expf(val[k] - mx); s += w[k]; }
        float inv = 1.0f / s;
        #pragma unroll
        for (int k = 0; k < K_; k++) {
            topi[t*K_ + k] = idx[k];
            topw[t*K_ + k] = w[k] * inv;
        }
    }
}

__global__ void bucket_kernel(const int* __restrict__ topi, const float* __restrict__ topw,
                              int* __restrict__ counts,
                              int* __restrict__ bucket_tok, float* __restrict__ bucket_w)
{
    int i = blockIdx.x * 256 + threadIdx.x;
    if (i >= NPAIR) return;
    int t = i >> 2;
    int e = topi[i];
    int pos = atomicAdd(&counts[e], 1);
    bucket_tok[e * NTOK + pos] = t;
    bucket_w [e * NTOK + pos] = topw[i];
}

__global__ void scan_kernel(const int* __restrict__ counts, int* __restrict__ offsets)
{
    if (threadIdx.x == 0) {
        int s = 0;
        for (int e = 0; e < E_; e++) { offsets[e] = s; s += counts[e]; }
        offsets[E_] = s;
    }
}

// ==================== GEMM1: hidden = gelu(x_g @ w1^T + b1) ====================
// 128x128 tile, BK=64, double-buffered LDS, 1 barrier per K-tile (2-phase),
// source-side XOR slot swizzle (slot ^= row&7) -> conflict-free frag reads.
#define G1_BLOCKS (16*32*16)
__global__ __launch_bounds__(256, 2) void gemm1_kernel(
    const unsigned short* __restrict__ xb, const unsigned short* __restrict__ w1b,
    const float* __restrict__ b1,
    const int* __restrict__ counts, const int* __restrict__ offsets,
    const int* __restrict__ bucket_tok, unsigned short* __restrict__ hidden)
{
    int id = xcdmap(blockIdx.x, G1_BLOCKS);
    int y = id & 15, n = (id >> 4) & 31, e = id >> 9;   // y fastest: same-B-panel adjacent
    int Te = counts[e];
    int row0 = y * 128;
    if (row0 >= Te) return;
    int f0 = n * 128;
    int tid = threadIdx.x;
    int lane = tid & 63, w = tid >> 6;

    __shared__ unsigned short As[2][128][64];
    __shared__ unsigned short Bs[2][128][64];
    __shared__ int toks[128];

    if (tid < 128) {
        int r = row0 + tid;
        toks[tid] = bucket_tok[e * NTOK + (r < Te ? r : Te - 1)];
    }
    __syncthreads();

    // staging geometry: batch b covers rows 32b..32b+31; wave w covers rows 8w..8w+7 within batch
    int lr3 = (lane >> 3) & 7;                   // == row & 7
    int slg = (lane & 7) ^ lr3;                  // swizzled source slot
    const unsigned short* pa[4];
    const unsigned short* pb[4];
    unsigned short* da[4];
    unsigned short* db[4];
    #pragma unroll
    for (int b = 0; b < 4; b++) {
        int row = 32 * b + 8 * w + lr3;
        pa[b] = xb  + (size_t)toks[row] * D_ + slg * 8;
        pb[b] = w1b + ((size_t)e * F_ + f0 + row) * D_ + slg * 8;
        da[b] = &As[0][32 * b + 8 * w][0];       // wave-uniform base (lr3/slg are lane-local,
        db[b] = &Bs[0][32 * b + 8 * w][0];       //  row base uses only b,w)
    }
    const size_t bufstep = 128 * 64;             // elements between As[0] and As[1]

    int lr = lane & 15, q = lane >> 4;
    int col0 = ((q ^ (lr & 7)) * 8);             // swizzled frag-read column (elements)
    int wr = w >> 1, wc = w & 1;

    f32x4 acc[4][4];
    #pragma unroll
    for (int m = 0; m < 4; m++)
        #pragma unroll
        for (int nn = 0; nn < 4; nn++) acc[m][nn] = (f32x4){0.f,0.f,0.f,0.f};

    #define G1_STAGE(nb, k0) { \
        _Pragma("unroll") \
        for (int b = 0; b < 4; b++) { \
            GLOAD16(pa[b] + (k0), da[b] + (nb) * bufstep); \
            GLOAD16(pb[b] + (k0), db[b] + (nb) * bufstep); \
        } }

    #define G1_COMPUTE(cb) { \
        bf16x8 af[4][2], bfr[4][2]; \
        _Pragma("unroll") \
        for (int m = 0; m < 4; m++) { \
            int r = wr*64 + m*16 + lr; \
            af[m][0] = *reinterpret_cast<const bf16x8*>(&As[cb][r][col0]); \
            af[m][1] = *reinterpret_cast<const bf16x8*>(&As[cb][r][col0 ^ 32]); \
        } \
        _Pragma("unroll") \
        for (int nn = 0; nn < 4; nn++) { \
            int r = wc*64 + nn*16 + lr; \
            bfr[nn][0] = *reinterpret_cast<const bf16x8*>(&Bs[cb][r][col0]); \
            bfr[nn][1] = *reinterpret_cast<const bf16x8*>(&Bs[cb][r][col0 ^ 32]); \
        } \
        _Pragma("unroll") \
        for (int kk = 0; kk < 2; kk++) \
            _Pragma("unroll") \
            for (int m = 0; m < 4; m++) \
                _Pragma("unroll") \
                for (int nn = 0; nn < 4; nn++) \
                    acc[m][nn] = __builtin_amdgcn_mfma_f32_16x16x32_bf16(af[m][kk], bfr[nn][kk], acc[m][nn], 0, 0, 0); \
        }

    G1_STAGE(0, 0);
    __syncthreads();                             // drains vmcnt(0): buf0 ready
    int cur = 0;
    for (int kt = 1; kt < D_ / 64; ++kt) {
        G1_STAGE(cur ^ 1, kt * 64);
        G1_COMPUTE(cur);
        __syncthreads();                         // all reads of cur done; next buf landed
        cur ^= 1;
    }
    G1_COMPUTE(cur);

    int obase = offsets[e];
    #pragma unroll
    for (int m = 0; m < 4; m++) {
        int rbase = wr*64 + m*16 + q * 4;
        #pragma unroll
        for (int nn = 0; nn < 4; nn++) {
            int gcol = f0 + wc*64 + nn*16 + lr;
            float bias = b1[e * F_ + gcol];
            #pragma unroll
            for (int r = 0; r < 4; r++) {
                int lrow = rbase + r;
                if (row0 + lrow < Te) {
                    float v = acc[m][nn][r] + bias;
                    float g = 0.5f * v * (1.0f + erff(v * 0.70710678118654752f));
                    hidden[(size_t)(obase + row0 + lrow) * F_ + gcol] =
                        __builtin_bit_cast(unsigned short, (__bf16)g);
                }
            }
        }
    }
}

// ==================== GEMM2: out += gate_w * (hidden @ w2^T + b2) ====================
#define G2_BLOCKS (16*8*16)
__global__ __launch_bounds__(256, 2) void gemm2_kernel(
    const unsigned short* __restrict__ hidden, const unsigned short* __restrict__ w2b,
    const float* __restrict__ b2,
    const int* __restrict__ counts, const int* __restrict__ offsets,
    const int* __restrict__ bucket_tok, const float* __restrict__ bucket_w,
    float* __restrict__ out)
{
    int id = xcdmap(blockIdx.x, G2_BLOCKS);
    int y = id & 15, n = (id >> 4) & 7, e = id >> 7;
    int Te = counts[e];
    int row0 = y * 128;
    if (row0 >= Te) return;
    int n0 = n * 128;
    int tid = threadIdx.x;
    int lane = tid & 63, w = tid >> 6;

    __shared__ unsigned short As[2][128][64];
    __shared__ unsigned short Bs[2][128][64];
    __shared__ int   toks[128];
    __shared__ float wts [128];

    int obase = offsets[e];
    if (tid < 128) {
        int r = row0 + tid;
        int rc = (r < Te ? r : Te - 1);
        toks[tid] = bucket_tok[e * NTOK + rc];
        wts [tid] = bucket_w [e * NTOK + rc];
    }
    __syncthreads();

    int lr3 = (lane >> 3) & 7;
    int slg = (lane & 7) ^ lr3;
    const unsigned short* pa[4];
    const unsigned short* pb[4];
    unsigned short* da[4];
    unsigned short* db[4];
    #pragma unroll
    for (int b = 0; b < 4; b++) {
        int row = 32 * b + 8 * w + lr3;
        int ar = row0 + row; ar = (ar < Te ? ar : Te - 1);
        pa[b] = hidden + (size_t)(obase + ar) * F_ + slg * 8;
        pb[b] = w2b + ((size_t)e * D_ + n0 + row) * F_ + slg * 8;
        da[b] = &As[0][32 * b + 8 * w][0];
        db[b] = &Bs[0][32 * b + 8 * w][0];
    }
    const size_t bufstep = 128 * 64;

    int lr = lane & 15, q = lane >> 4;
    int col0 = ((q ^ (lr & 7)) * 8);
    int wr = w >> 1, wc = w & 1;

    f32x4 acc[4][4];
    #pragma unroll
    for (int m = 0; m < 4; m++)
        #pragma unroll
        for (int nn = 0; nn < 4; nn++) acc[m][nn] = (f32x4){0.f,0.f,0.f,0.f};

    G1_STAGE(0, 0);
    __syncthreads();
    int cur = 0;
    for (int kt = 1; kt < F_ / 64; ++kt) {
        G1_STAGE(cur ^ 1, kt * 64);
        G1_COMPUTE(cur);
        __syncthreads();
        cur ^= 1;
    }
    G1_COMPUTE(cur);

    #pragma unroll
    for (int m = 0; m < 4; m++) {
        int rbase = wr*64 + m*16 + q * 4;
        #pragma unroll
        for (int nn = 0; nn < 4; nn++) {
            int gcol = n0 + wc*64 + nn*16 + lr;
            float bias = b2[e * D_ + gcol];
            #pragma unroll
            for (int r = 0; r < 4; r++) {
                int lrow = rbase + r;
                if (row0 + lrow < Te) {
                    float v = acc[m][nn][r] + bias;
                    atomicAdd(&out[(size_t)toks[lrow] * D_ + gcol], wts[lrow] * v);
                }
            }
        }
    }
}

extern "C" void kernel_launch(void* const* d_in, const int* in_sizes, int n_in,
                              void* d_out, int out_size, void* d_ws, size_t ws_size,
                              hipStream_t stream)
{
    const float* x    = (const float*)d_in[0];
    const float* keys = (const float*)d_in[1];
    const float* w1   = (const float*)d_in[2];
    const float* b1   = (const float*)d_in[3];
    const float* w2   = (const float*)d_in[4];
    const float* b2   = (const float*)d_in[5];
    const float* rw   = (const float*)d_in[6];
    const float* rb   = (const float*)d_in[7];
    float* out = (float*)d_out;

    char* wsp = (char*)d_ws;
    size_t off = 0;
    auto alloc = [&](size_t bytes) -> char* {
        char* p = wsp + off;
        off = (off + bytes + 255) & ~(size_t)255;
        return p;
    };
    int*   topi       = (int*)  alloc(NPAIR * sizeof(int));
    float* topw       = (float*)alloc(NPAIR * sizeof(float));
    int*   counts     = (int*)  alloc(E_ * sizeof(int));
    int*   offsets    = (int*)  alloc((E_ + 1) * sizeof(int));
    int*   bucket_tok = (int*)  alloc((size_t)E_ * NTOK * sizeof(int));
    float* bucket_w   = (float*)alloc((size_t)E_ * NTOK * sizeof(float));
    unsigned short* xb     = (unsigned short*)alloc((size_t)NTOK * D_ * sizeof(unsigned short));
    unsigned short* w1b    = (unsigned short*)alloc((size_t)E_ * F_ * D_ * sizeof(unsigned short));
    unsigned short* w2b    = (unsigned short*)alloc((size_t)E_ * D_ * F_ * sizeof(unsigned short));
    unsigned short* hidden = (unsigned short*)alloc((size_t)NPAIR * F_ * sizeof(unsigned short));

    hipMemsetAsync(d_out, 0, (size_t)out_size * sizeof(float), stream);

    router_kernel<<<NTOK, 256, 0, stream>>>(x, keys, rw, rb, topi, topw, counts);
    bucket_kernel<<<NPAIR / 256, 256, 0, stream>>>(topi, topw, counts, bucket_tok, bucket_w);
    scan_kernel<<<1, 64, 0, stream>>>(counts, offsets);

    cvt_kernel<<<(NTOK * D_) / 4096, 256, 0, stream>>>(x, xb);
    cvt_kernel<<<(E_ * F_ * D_) / 4096, 256, 0, stream>>>(w1, w1b);
    cvt_kernel<<<(E_ * D_ * F_) / 4096, 256, 0, stream>>>(w2, w2b);

    gemm1_kernel<<<G1_BLOCKS, 256, 0, stream>>>(
        xb, w1b, b1, counts, offsets, bucket_tok, hidden);
    gemm2_kernel<<<G2_BLOCKS, 256, 0, stream>>>(
        hidden, w2b, b2, counts, offsets, bucket_tok, bucket_w, out);
}

// Round 11
// 1066.469 us; speedup vs baseline: 1.2029x; 1.2029x over previous
//
#include <hip/hip_runtime.h>

#define B_ 4
#define L_ 512
#define D_ 1024
#define E_ 16
#define K_ 4
#define F_ 4096
#define NTOK (B_*L_)      // 2048
#define NPAIR (NTOK*K_)   // 8192

typedef float f32x4 __attribute__((ext_vector_type(4)));
typedef __bf16 bf16x8 __attribute__((ext_vector_type(8)));

__device__ inline unsigned int pack2(float a, float b) {
    unsigned short ua = __builtin_bit_cast(unsigned short, (__bf16)a);
    unsigned short ub = __builtin_bit_cast(unsigned short, (__bf16)b);
    return (unsigned int)ua | ((unsigned int)ub << 16);
}

#define GLOAD16(g, l) __builtin_amdgcn_global_load_lds( \
    (const __attribute__((address_space(1))) void*)(g), \
    (__attribute__((address_space(3))) void*)(l), 16, 0, 0)

// Balanced cluster-preserving XCD map (nwg % 128 == 0).
// Hardware round-robins orig over 8 XCDs (orig&7). We keep each 16-id
// y-cluster (one (e,n) panel group) contiguous on ONE XCD for L2 panel
// reuse, but round-robin the GROUPS over XCDs so expert identity does not
// correlate with XCD (expert load is skewed; e-chunking serialized one XCD).
__device__ inline int xcdmap16(int orig) {
    int xcd = orig & 7;
    int s   = orig >> 3;          // sequence within this XCD
    int g   = xcd + 8 * (s >> 4); // group index, round-robin over XCDs
    int y   = s & 15;             // y-position within the cluster
    return g * 16 + y;
}

// ---------------- fp32 -> bf16 bulk convert (16 elems/thread) ----------------
__global__ __launch_bounds__(256) void cvt_kernel(const float* __restrict__ src,
                                                  unsigned short* __restrict__ dst)
{
    size_t i = ((size_t)blockIdx.x * 256 + threadIdx.x) * 16;
    const float4* s = reinterpret_cast<const float4*>(src + i);
    float4 v0 = s[0], v1 = s[1], v2 = s[2], v3 = s[3];
    uint4 p0 = { pack2(v0.x,v0.y), pack2(v0.z,v0.w), pack2(v1.x,v1.y), pack2(v1.z,v1.w) };
    uint4 p1 = { pack2(v2.x,v2.y), pack2(v2.z,v2.w), pack2(v3.x,v3.y), pack2(v3.z,v3.w) };
    uint4* d = reinterpret_cast<uint4*>(dst + i);
    d[0] = p0; d[1] = p1;
}

// ---------------- Router ----------------
__global__ __launch_bounds__(256) void router_kernel(
    const float* __restrict__ x, const float* __restrict__ keys,
    const float* __restrict__ rw, const float* __restrict__ rb,
    int* __restrict__ topi, float* __restrict__ topw, int* __restrict__ counts)
{
    int t = blockIdx.x;
    int tid = threadIdx.x;
    if (blockIdx.x == 0 && tid < E_) counts[tid] = 0;

    __shared__ float xs[D_];
    const float* xrow = x + (size_t)t * D_;
    for (int i = tid; i < D_; i += 256) xs[i] = xrow[i];
    __syncthreads();

    int e    = tid >> 4;
    int lane = tid & 15;
    const float* krow = keys + e * D_;
    const float* rrow = rw   + e * D_;
    double dist2 = 0.0, dot = 0.0;
    for (int d = lane; d < D_; d += 16) {
        float xv = xs[d];
        float df = xv - krow[d];
        dist2 += (double)df * df;
        dot   += (double)xv * rrow[d];
    }
    #pragma unroll
    for (int m = 8; m >= 1; m >>= 1) {
        dist2 += __shfl_xor(dist2, m);
        dot   += __shfl_xor(dot, m);
    }
    __shared__ float lg[E_];
    if (lane == 0) lg[e] = (float)(-dist2 + dot) + rb[e];
    __syncthreads();

    if (tid == 0) {
        float v[E_];
        #pragma unroll
        for (int i = 0; i < E_; i++) v[i] = lg[i];
        int   idx[K_]; float val[K_];
        #pragma unroll
        for (int k = 0; k < K_; k++) {
            int bi = 0; float bv = -1e30f;
            #pragma unroll
            for (int i = 0; i < E_; i++) if (v[i] > bv) { bv = v[i]; bi = i; }
            idx[k] = bi; val[k] = bv; v[bi] = -1e30f;
        }
        float mx = val[0], s = 0.f, w[K_];
        #pragma unroll
        for (int k = 0; k < K_; k++) { w[k] = expf(val[k] - mx); s += w[k]; }
        float inv = 1.0f / s;
        #pragma unroll
        for (int k = 0; k < K_; k++) {
            topi[t*K_ + k] = idx[k];
            topw[t*K_ + k] = w[k] * inv;
        }
    }
}

__global__ void bucket_kernel(const int* __restrict__ topi, const float* __restrict__ topw,
                              int* __restrict__ counts,
                              int* __restrict__ bucket_tok, float* __restrict__ bucket_w)
{
    int i = blockIdx.x * 256 + threadIdx.x;
    if (i >= NPAIR) return;
    int t = i >> 2;
    int e = topi[i];
    int pos = atomicAdd(&counts[e], 1);
    bucket_tok[e * NTOK + pos] = t;
    bucket_w [e * NTOK + pos] = topw[i];
}

__global__ void scan_kernel(const int* __restrict__ counts, int* __restrict__ offsets)
{
    if (threadIdx.x == 0) {
        int s = 0;
        for (int e = 0; e < E_; e++) { offsets[e] = s; s += counts[e]; }
        offsets[E_] = s;
    }
}

// ==================== GEMM1: hidden = gelu(x_g @ w1^T + b1) ====================
// 128x128 tile, BK=64, double-buffered LDS, 1 barrier per K-tile (2-phase),
// source-side XOR slot swizzle (slot ^= row&7) -> conflict-free frag reads.
#define G1_BLOCKS (16*32*16)
__global__ __launch_bounds__(256, 2) void gemm1_kernel(
    const unsigned short* __restrict__ xb, const unsigned short* __restrict__ w1b,
    const float* __restrict__ b1,
    const int* __restrict__ counts, const int* __restrict__ offsets,
    const int* __restrict__ bucket_tok, unsigned short* __restrict__ hidden)
{
    int id = xcdmap16(blockIdx.x);
    int y = id & 15, n = (id >> 4) & 31, e = id >> 9;   // y fastest within a cluster
    int Te = counts[e];
    int row0 = y * 128;
    if (row0 >= Te) return;
    int f0 = n * 128;
    int tid = threadIdx.x;
    int lane = tid & 63, w = tid >> 6;

    __shared__ unsigned short As[2][128][64];
    __shared__ unsigned short Bs[2][128][64];
    __shared__ int toks[128];

    if (tid < 128) {
        int r = row0 + tid;
        toks[tid] = bucket_tok[e * NTOK + (r < Te ? r : Te - 1)];
    }
    __syncthreads();

    // staging geometry: batch b covers rows 32b..32b+31; wave w covers rows 8w..8w+7 within batch
    int lr3 = (lane >> 3) & 7;                   // == row & 7
    int slg = (lane & 7) ^ lr3;                  // swizzled source slot
    const unsigned short* pa[4];
    const unsigned short* pb[4];
    unsigned short* da[4];
    unsigned short* db[4];
    #pragma unroll
    for (int b = 0; b < 4; b++) {
        int row = 32 * b + 8 * w + lr3;
        pa[b] = xb  + (size_t)toks[row] * D_ + slg * 8;
        pb[b] = w1b + ((size_t)e * F_ + f0 + row) * D_ + slg * 8;
        da[b] = &As[0][32 * b + 8 * w][0];       // wave-uniform base
        db[b] = &Bs[0][32 * b + 8 * w][0];
    }
    const size_t bufstep = 128 * 64;

    int lr = lane & 15, q = lane >> 4;
    int col0 = ((q ^ (lr & 7)) * 8);             // swizzled frag-read column (elements)
    int wr = w >> 1, wc = w & 1;

    f32x4 acc[4][4];
    #pragma unroll
    for (int m = 0; m < 4; m++)
        #pragma unroll
        for (int nn = 0; nn < 4; nn++) acc[m][nn] = (f32x4){0.f,0.f,0.f,0.f};

    #define G1_STAGE(nb, k0) { \
        _Pragma("unroll") \
        for (int b = 0; b < 4; b++) { \
            GLOAD16(pa[b] + (k0), da[b] + (nb) * bufstep); \
            GLOAD16(pb[b] + (k0), db[b] + (nb) * bufstep); \
        } }

    #define G1_COMPUTE(cb) { \
        bf16x8 af[4][2], bfr[4][2]; \
        _Pragma("unroll") \
        for (int m = 0; m < 4; m++) { \
            int r = wr*64 + m*16 + lr; \
            af[m][0] = *reinterpret_cast<const bf16x8*>(&As[cb][r][col0]); \
            af[m][1] = *reinterpret_cast<const bf16x8*>(&As[cb][r][col0 ^ 32]); \
        } \
        _Pragma("unroll") \
        for (int nn = 0; nn < 4; nn++) { \
            int r = wc*64 + nn*16 + lr; \
            bfr[nn][0] = *reinterpret_cast<const bf16x8*>(&Bs[cb][r][col0]); \
            bfr[nn][1] = *reinterpret_cast<const bf16x8*>(&Bs[cb][r][col0 ^ 32]); \
        } \
        _Pragma("unroll") \
        for (int kk = 0; kk < 2; kk++) \
            _Pragma("unroll") \
            for (int m = 0; m < 4; m++) \
                _Pragma("unroll") \
                for (int nn = 0; nn < 4; nn++) \
                    acc[m][nn] = __builtin_amdgcn_mfma_f32_16x16x32_bf16(af[m][kk], bfr[nn][kk], acc[m][nn], 0, 0, 0); \
        }

    G1_STAGE(0, 0);
    __syncthreads();                             // drains vmcnt(0): buf0 ready
    int cur = 0;
    for (int kt = 1; kt < D_ / 64; ++kt) {
        G1_STAGE(cur ^ 1, kt * 64);
        G1_COMPUTE(cur);
        __syncthreads();                         // all reads of cur done; next buf landed
        cur ^= 1;
    }
    G1_COMPUTE(cur);

    int obase = offsets[e];
    #pragma unroll
    for (int m = 0; m < 4; m++) {
        int rbase = wr*64 + m*16 + q * 4;
        #pragma unroll
        for (int nn = 0; nn < 4; nn++) {
            int gcol = f0 + wc*64 + nn*16 + lr;
            float bias = b1[e * F_ + gcol];
            #pragma unroll
            for (int r = 0; r < 4; r++) {
                int lrow = rbase + r;
                if (row0 + lrow < Te) {
                    float v = acc[m][nn][r] + bias;
                    float g = 0.5f * v * (1.0f + erff(v * 0.70710678118654752f));
                    hidden[(size_t)(obase + row0 + lrow) * F_ + gcol] =
                        __builtin_bit_cast(unsigned short, (__bf16)g);
                }
            }
        }
    }
}

// ==================== GEMM2: out += gate_w * (hidden @ w2^T + b2) ====================
#define G2_BLOCKS (16*8*16)
__global__ __launch_bounds__(256, 2) void gemm2_kernel(
    const unsigned short* __restrict__ hidden, const unsigned short* __restrict__ w2b,
    const float* __restrict__ b2,
    const int* __restrict__ counts, const int* __restrict__ offsets,
    const int* __restrict__ bucket_tok, const float* __restrict__ bucket_w,
    float* __restrict__ out)
{
    int id = xcdmap16(blockIdx.x);
    int y = id & 15, n = (id >> 4) & 7, e = id >> 7;
    int Te = counts[e];
    int row0 = y * 128;
    if (row0 >= Te) return;
    int n0 = n * 128;
    int tid = threadIdx.x;
    int lane = tid & 63, w = tid >> 6;

    __shared__ unsigned short As[2][128][64];
    __shared__ unsigned short Bs[2][128][64];
    __shared__ int   toks[128];
    __shared__ float wts [128];

    int obase = offsets[e];
    if (tid < 128) {
        int r = row0 + tid;
        int rc = (r < Te ? r : Te - 1);
        toks[tid] = bucket_tok[e * NTOK + rc];
        wts [tid] = bucket_w [e * NTOK + rc];
    }
    __syncthreads();

    int lr3 = (lane >> 3) & 7;
    int slg = (lane & 7) ^ lr3;
    const unsigned short* pa[4];
    const unsigned short* pb[4];
    unsigned short* da[4];
    unsigned short* db[4];
    #pragma unroll
    for (int b = 0; b < 4; b++) {
        int row = 32 * b + 8 * w + lr3;
        int ar = row0 + row; ar = (ar < Te ? ar : Te - 1);
        pa[b] = hidden + (size_t)(obase + ar) * F_ + slg * 8;
        pb[b] = w2b + ((size_t)e * D_ + n0 + row) * F_ + slg * 8;
        da[b] = &As[0][32 * b + 8 * w][0];
        db[b] = &Bs[0][32 * b + 8 * w][0];
    }
    const size_t bufstep = 128 * 64;

    int lr = lane & 15, q = lane >> 4;
    int col0 = ((q ^ (lr & 7)) * 8);
    int wr = w >> 1, wc = w & 1;

    f32x4 acc[4][4];
    #pragma unroll
    for (int m = 0; m < 4; m++)
        #pragma unroll
        for (int nn = 0; nn < 4; nn++) acc[m][nn] = (f32x4){0.f,0.f,0.f,0.f};

    G1_STAGE(0, 0);
    __syncthreads();
    int cur = 0;
    for (int kt = 1; kt < F_ / 64; ++kt) {
        G1_STAGE(cur ^ 1, kt * 64);
        G1_COMPUTE(cur);
        __syncthreads();
        cur ^= 1;
    }
    G1_COMPUTE(cur);

    #pragma unroll
    for (int m = 0; m < 4; m++) {
        int rbase = wr*64 + m*16 + q * 4;
        #pragma unroll
        for (int nn = 0; nn < 4; nn++) {
            int gcol = n0 + wc*64 + nn*16 + lr;
            float bias = b2[e * D_ + gcol];
            #pragma unroll
            for (int r = 0; r < 4; r++) {
                int lrow = rbase + r;
                if (row0 + lrow < Te) {
                    float v = acc[m][nn][r] + bias;
                    atomicAdd(&out[(size_t)toks[lrow] * D_ + gcol], wts[lrow] * v);
                }
            }
        }
    }
}

extern "C" void kernel_launch(void* const* d_in, const int* in_sizes, int n_in,
                              void* d_out, int out_size, void* d_ws, size_t ws_size,
                              hipStream_t stream)
{
    const float* x    = (const float*)d_in[0];
    const float* keys = (const float*)d_in[1];
    const float* w1   = (const float*)d_in[2];
    const float* b1   = (const float*)d_in[3];
    const float* w2   = (const float*)d_in[4];
    const float* b2   = (const float*)d_in[5];
    const float* rw   = (const float*)d_in[6];
    const float* rb   = (const float*)d_in[7];
    float* out = (float*)d_out;

    char* wsp = (char*)d_ws;
    size_t off = 0;
    auto alloc = [&](size_t bytes) -> char* {
        char* p = wsp + off;
        off = (off + bytes + 255) & ~(size_t)255;
        return p;
    };
    int*   topi       = (int*)  alloc(NPAIR * sizeof(int));
    float* topw       = (float*)alloc(NPAIR * sizeof(float));
    int*   counts     = (int*)  alloc(E_ * sizeof(int));
    int*   offsets    = (int*)  alloc((E_ + 1) * sizeof(int));
    int*   bucket_tok = (int*)  alloc((size_t)E_ * NTOK * sizeof(int));
    float* bucket_w   = (float*)alloc((size_t)E_ * NTOK * sizeof(float));
    unsigned short* xb     = (unsigned short*)alloc((size_t)NTOK * D_ * sizeof(unsigned short));
    unsigned short* w1b    = (unsigned short*)alloc((size_t)E_ * F_ * D_ * sizeof(unsigned short));
    unsigned short* w2b    = (unsigned short*)alloc((size_t)E_ * D_ * F_ * sizeof(unsigned short));
    unsigned short* hidden = (unsigned short*)alloc((size_t)NPAIR * F_ * sizeof(unsigned short));

    hipMemsetAsync(d_out, 0, (size_t)out_size * sizeof(float), stream);

    router_kernel<<<NTOK, 256, 0, stream>>>(x, keys, rw, rb, topi, topw, counts);
    bucket_kernel<<<NPAIR / 256, 256, 0, stream>>>(topi, topw, counts, bucket_tok, bucket_w);
    scan_kernel<<<1, 64, 0, stream>>>(counts, offsets);

    cvt_kernel<<<(NTOK * D_) / 4096, 256, 0, stream>>>(x, xb);
    cvt_kernel<<<(E_ * F_ * D_) / 4096, 256, 0, stream>>>(w1, w1b);
    cvt_kernel<<<(E_ * D_ * F_) / 4096, 256, 0, stream>>>(w2, w2b);

    gemm1_kernel<<<G1_BLOCKS, 256, 0, stream>>>(
        xb, w1b, b1, counts, offsets, bucket_tok, hidden);
    gemm2_kernel<<<G2_BLOCKS, 256, 0, stream>>>(
        hidden, w2b, b2, counts, offsets, bucket_tok, bucket_w, out);
}

// Round 13
// 1006.152 us; speedup vs baseline: 1.2751x; 1.0599x over previous
//
#include <hip/hip_runtime.h>

#define B_ 4
#define L_ 512
#define D_ 1024
#define E_ 16
#define K_ 4
#define F_ 4096
#define NTOK (B_*L_)      // 2048
#define NPAIR (NTOK*K_)   // 8192
#define Q1CAP 2048        // per-queue capacity, gemm1 (total items <= 8192)
#define Q2CAP 512         // per-queue capacity, gemm2 (total items <= 2048)

typedef float f32x4 __attribute__((ext_vector_type(4)));
typedef __bf16 bf16x8 __attribute__((ext_vector_type(8)));

__device__ inline unsigned int pack2(float a, float b) {
    unsigned short ua = __builtin_bit_cast(unsigned short, (__bf16)a);
    unsigned short ub = __builtin_bit_cast(unsigned short, (__bf16)b);
    return (unsigned int)ua | ((unsigned int)ub << 16);
}

#define GLOAD16(g, l) __builtin_amdgcn_global_load_lds( \
    (const __attribute__((address_space(1))) void*)(g), \
    (__attribute__((address_space(3))) void*)(l), 16, 0, 0)

// ---------------- fp32 -> bf16 bulk convert ----------------
__global__ __launch_bounds__(256) void cvt_kernel(const float* __restrict__ src,
                                                  unsigned short* __restrict__ dst)
{
    size_t i = ((size_t)blockIdx.x * 256 + threadIdx.x) * 16;
    const float4* s = reinterpret_cast<const float4*>(src + i);
    float4 v0 = s[0], v1 = s[1], v2 = s[2], v3 = s[3];
    uint4 p0 = { pack2(v0.x,v0.y), pack2(v0.z,v0.w), pack2(v1.x,v1.y), pack2(v1.z,v1.w) };
    uint4 p1 = { pack2(v2.x,v2.y), pack2(v2.z,v2.w), pack2(v3.x,v3.y), pack2(v3.z,v3.w) };
    uint4* d = reinterpret_cast<uint4*>(dst + i);
    d[0] = p0; d[1] = p1;
}

// weight convert, skipping experts with zero tokens (data-dependent but
// deterministic per input -> graph-capture safe)
__global__ __launch_bounds__(256) void cvtw_kernel(const float* __restrict__ src,
                                                   unsigned short* __restrict__ dst,
                                                   const int* __restrict__ counts)
{
    int e = blockIdx.y;
    if (counts[e] == 0) return;
    size_t i = (size_t)e * F_ * D_ + ((size_t)blockIdx.x * 256 + threadIdx.x) * 16;
    const float4* s = reinterpret_cast<const float4*>(src + i);
    float4 v0 = s[0], v1 = s[1], v2 = s[2], v3 = s[3];
    uint4 p0 = { pack2(v0.x,v0.y), pack2(v0.z,v0.w), pack2(v1.x,v1.y), pack2(v1.z,v1.w) };
    uint4 p1 = { pack2(v2.x,v2.y), pack2(v2.z,v2.w), pack2(v3.x,v3.y), pack2(v3.z,v3.w) };
    uint4* d = reinterpret_cast<uint4*>(dst + i);
    d[0] = p0; d[1] = p1;
}

// ---------------- Router ----------------
__global__ __launch_bounds__(256) void router_kernel(
    const float* __restrict__ x, const float* __restrict__ keys,
    const float* __restrict__ rw, const float* __restrict__ rb,
    int* __restrict__ topi, float* __restrict__ topw, int* __restrict__ counts)
{
    int t = blockIdx.x;
    int tid = threadIdx.x;
    if (blockIdx.x == 0 && tid < E_) counts[tid] = 0;

    __shared__ float xs[D_];
    const float* xrow = x + (size_t)t * D_;
    for (int i = tid; i < D_; i += 256) xs[i] = xrow[i];
    __syncthreads();

    int e    = tid >> 4;
    int lane = tid & 15;
    const float* krow = keys + e * D_;
    const float* rrow = rw   + e * D_;
    double dist2 = 0.0, dot = 0.0;
    for (int d = lane; d < D_; d += 16) {
        float xv = xs[d];
        float df = xv - krow[d];
        dist2 += (double)df * df;
        dot   += (double)xv * rrow[d];
    }
    #pragma unroll
    for (int m = 8; m >= 1; m >>= 1) {
        dist2 += __shfl_xor(dist2, m);
        dot   += __shfl_xor(dot, m);
    }
    __shared__ float lg[E_];
    if (lane == 0) lg[e] = (float)(-dist2 + dot) + rb[e];
    __syncthreads();

    if (tid == 0) {
        float v[E_];
        #pragma unroll
        for (int i = 0; i < E_; i++) v[i] = lg[i];
        int   idx[K_]; float val[K_];
        #pragma unroll
        for (int k = 0; k < K_; k++) {
            int bi = 0; float bv = -1e30f;
            #pragma unroll
            for (int i = 0; i < E_; i++) if (v[i] > bv) { bv = v[i]; bi = i; }
            idx[k] = bi; val[k] = bv; v[bi] = -1e30f;
        }
        float mx = val[0], s = 0.f, w[K_];
        #pragma unroll
        for (int k = 0; k < K_; k++) { w[k] = expf(val[k] - mx); s += w[k]; }
        float inv = 1.0f / s;
        #pragma unroll
        for (int k = 0; k < K_; k++) {
            topi[t*K_ + k] = idx[k];
            topw[t*K_ + k] = w[k] * inv;
        }
    }
}

__global__ void bucket_kernel(const int* __restrict__ topi, const float* __restrict__ topw,
                              int* __restrict__ counts,
                              int* __restrict__ bucket_tok, float* __restrict__ bucket_w)
{
    int i = blockIdx.x * 256 + threadIdx.x;
    if (i >= NPAIR) return;
    int t = i >> 2;
    int e = topi[i];
    int pos = atomicAdd(&counts[e], 1);
    bucket_tok[e * NTOK + pos] = t;
    bucket_w [e * NTOK + pos] = topw[i];
}

__global__ void scan_kernel(const int* __restrict__ counts, int* __restrict__ offsets)
{
    if (threadIdx.x == 0) {
        int s = 0;
        for (int e = 0; e < E_; e++) { offsets[e] = s; s += counts[e]; }
        offsets[E_] = s;
    }
}

// ---------------- Planner: build per-XCD work queues of ACTIVE tiles ----------------
// gemm1 cluster (e,n<32) -> queue n&7; gemm2 cluster (e,n<8) -> queue n.
// Every queue gets identical load (4*sum(yb) / sum(yb)) -> perfectly balanced.
// Items of one cluster are contiguous -> its XCD reuses the B panel via L2.
__global__ __launch_bounds__(512) void plan_kernel(
    const int* __restrict__ counts,
    int* __restrict__ q1, int* __restrict__ q1len,
    int* __restrict__ q2, int* __restrict__ q2len,
    int* __restrict__ qheads)
{
    int tid = threadIdx.x;
    if (tid < 16) qheads[tid] = 0;
    __shared__ int yb[E_], cum[E_ + 1];
    if (tid == 0) {
        int s = 0;
        for (int e = 0; e < E_; e++) { cum[e] = s; yb[e] = (counts[e] + 127) >> 7; s += yb[e]; }
        cum[E_] = s;
    }
    __syncthreads();
    {   // gemm1: 512 clusters
        int e = tid >> 5, n = tid & 31;
        int q = n & 7, j = n >> 3;
        int off = 4 * cum[e] + j * yb[e];
        for (int y = 0; y < yb[e]; y++)
            q1[q * Q1CAP + off + y] = (e << 16) | (n << 8) | y;
    }
    if (tid < 128) {  // gemm2: 128 clusters
        int e = tid >> 3, n = tid & 7;
        int off = cum[e];
        for (int y = 0; y < yb[e]; y++)
            q2[n * Q2CAP + off + y] = (e << 16) | (n << 8) | y;
    }
    __syncthreads();
    if (tid < 8) { q1len[tid] = 4 * cum[E_]; q2len[tid] = cum[E_]; }
}

// ==================== GEMM1 (persistent): hidden = gelu(x_g @ w1^T + b1) ====================
// 128x128 tile, BK=64, double-buffered LDS, source-side XOR slot swizzle.
__global__ __launch_bounds__(256, 2) void gemm1_kernel(
    const unsigned short* __restrict__ xb, const unsigned short* __restrict__ w1b,
    const float* __restrict__ b1,
    const int* __restrict__ counts, const int* __restrict__ offsets,
    const int* __restrict__ bucket_tok, unsigned short* __restrict__ hidden,
    const int* __restrict__ q1, const int* __restrict__ q1len, int* __restrict__ qheads)
{
    int q = blockIdx.x & 7;                       // this block's XCD / queue
    int tid = threadIdx.x;
    int lane = tid & 63, w = tid >> 6;

    __shared__ unsigned short As[2][128][64];
    __shared__ unsigned short Bs[2][128][64];
    __shared__ int toks[128];
    __shared__ int item_s;

    // item-invariant geometry
    int lr3 = (lane >> 3) & 7;                    // row & 7
    int slg = (lane & 7) ^ lr3;                   // swizzled source slot
    unsigned short* da[4];
    unsigned short* db[4];
    #pragma unroll
    for (int b = 0; b < 4; b++) {
        da[b] = &As[0][32 * b + 8 * w][0];        // wave-uniform dest base
        db[b] = &Bs[0][32 * b + 8 * w][0];
    }
    const size_t bufstep = 128 * 64;
    int lr = lane & 15, qq = lane >> 4;
    int col0 = ((qq ^ (lr & 7)) * 8);             // swizzled frag-read column
    int wr = w >> 1, wc = w & 1;
    int len = q1len[q];

    for (;;) {
        __syncthreads();                          // protect LDS from prev item
        if (tid == 0) item_s = atomicAdd(&qheads[q], 1);
        __syncthreads();
        int it = item_s;
        if (it >= len) break;
        int packed = q1[q * Q1CAP + it];
        int e = packed >> 16, n = (packed >> 8) & 255, y = packed & 255;
        int Te = counts[e];
        int row0 = y * 128, f0 = n * 128;

        if (tid < 128) {
            int r = row0 + tid;
            toks[tid] = bucket_tok[e * NTOK + (r < Te ? r : Te - 1)];
        }
        __syncthreads();

        const unsigned short* pa[4];
        const unsigned short* pb[4];
        #pragma unroll
        for (int b = 0; b < 4; b++) {
            int row = 32 * b + 8 * w + lr3;
            pa[b] = xb  + (size_t)toks[row] * D_ + slg * 8;
            pb[b] = w1b + ((size_t)e * F_ + f0 + row) * D_ + slg * 8;
        }

        f32x4 acc[4][4];
        #pragma unroll
        for (int m = 0; m < 4; m++)
            #pragma unroll
            for (int nn = 0; nn < 4; nn++) acc[m][nn] = (f32x4){0.f,0.f,0.f,0.f};

        #define G1_STAGE(nb, k0) { \
            _Pragma("unroll") \
            for (int b = 0; b < 4; b++) { \
                GLOAD16(pa[b] + (k0), da[b] + (nb) * bufstep); \
                GLOAD16(pb[b] + (k0), db[b] + (nb) * bufstep); \
            } }

        #define G1_COMPUTE(cb) { \
            bf16x8 af[4][2], bfr[4][2]; \
            _Pragma("unroll") \
            for (int m = 0; m < 4; m++) { \
                int r = wr*64 + m*16 + lr; \
                af[m][0] = *reinterpret_cast<const bf16x8*>(&As[cb][r][col0]); \
                af[m][1] = *reinterpret_cast<const bf16x8*>(&As[cb][r][col0 ^ 32]); \
            } \
            _Pragma("unroll") \
            for (int nn = 0; nn < 4; nn++) { \
                int r = wc*64 + nn*16 + lr; \
                bfr[nn][0] = *reinterpret_cast<const bf16x8*>(&Bs[cb][r][col0]); \
                bfr[nn][1] = *reinterpret_cast<const bf16x8*>(&Bs[cb][r][col0 ^ 32]); \
            } \
            _Pragma("unroll") \
            for (int kk = 0; kk < 2; kk++) \
                _Pragma("unroll") \
                for (int m = 0; m < 4; m++) \
                    _Pragma("unroll") \
                    for (int nn = 0; nn < 4; nn++) \
                        acc[m][nn] = __builtin_amdgcn_mfma_f32_16x16x32_bf16(af[m][kk], bfr[nn][kk], acc[m][nn], 0, 0, 0); \
            }

        G1_STAGE(0, 0);
        __syncthreads();
        int cur = 0;
        for (int kt = 1; kt < D_ / 64; ++kt) {
            G1_STAGE(cur ^ 1, kt * 64);
            G1_COMPUTE(cur);
            __syncthreads();
            cur ^= 1;
        }
        G1_COMPUTE(cur);

        int obase = offsets[e];
        #pragma unroll
        for (int m = 0; m < 4; m++) {
            int rbase = wr*64 + m*16 + qq * 4;
            #pragma unroll
            for (int nn = 0; nn < 4; nn++) {
                int gcol = f0 + wc*64 + nn*16 + lr;
                float bias = b1[e * F_ + gcol];
                #pragma unroll
                for (int r = 0; r < 4; r++) {
                    int lrow = rbase + r;
                    if (row0 + lrow < Te) {
                        float v = acc[m][nn][r] + bias;
                        float g = 0.5f * v * (1.0f + erff(v * 0.70710678118654752f));
                        hidden[(size_t)(obase + row0 + lrow) * F_ + gcol] =
                            __builtin_bit_cast(unsigned short, (__bf16)g);
                    }
                }
            }
        }
    }
}

// ==================== GEMM2 (persistent): out += gate_w * (hidden @ w2^T + b2) ====================
__global__ __launch_bounds__(256, 2) void gemm2_kernel(
    const unsigned short* __restrict__ hidden, const unsigned short* __restrict__ w2b,
    const float* __restrict__ b2,
    const int* __restrict__ counts, const int* __restrict__ offsets,
    const int* __restrict__ bucket_tok, const float* __restrict__ bucket_w,
    float* __restrict__ out,
    const int* __restrict__ q2, const int* __restrict__ q2len, int* __restrict__ qheads)
{
    int q = blockIdx.x & 7;
    int tid = threadIdx.x;
    int lane = tid & 63, w = tid >> 6;

    __shared__ unsigned short As[2][128][64];
    __shared__ unsigned short Bs[2][128][64];
    __shared__ int   toks[128];
    __shared__ float wts [128];
    __shared__ int item_s;

    int lr3 = (lane >> 3) & 7;
    int slg = (lane & 7) ^ lr3;
    unsigned short* da[4];
    unsigned short* db[4];
    #pragma unroll
    for (int b = 0; b < 4; b++) {
        da[b] = &As[0][32 * b + 8 * w][0];
        db[b] = &Bs[0][32 * b + 8 * w][0];
    }
    const size_t bufstep = 128 * 64;
    int lr = lane & 15, qq = lane >> 4;
    int col0 = ((qq ^ (lr & 7)) * 8);
    int wr = w >> 1, wc = w & 1;
    int len = q2len[q];

    for (;;) {
        __syncthreads();
        if (tid == 0) item_s = atomicAdd(&qheads[8 + q], 1);
        __syncthreads();
        int it = item_s;
        if (it >= len) break;
        int packed = q2[q * Q2CAP + it];
        int e = packed >> 16, n = (packed >> 8) & 255, y = packed & 255;
        int Te = counts[e];
        int row0 = y * 128, n0 = n * 128;
        int obase = offsets[e];

        if (tid < 128) {
            int r = row0 + tid;
            int rc = (r < Te ? r : Te - 1);
            toks[tid] = bucket_tok[e * NTOK + rc];
            wts [tid] = bucket_w [e * NTOK + rc];
        }
        __syncthreads();

        const unsigned short* pa[4];
        const unsigned short* pb[4];
        #pragma unroll
        for (int b = 0; b < 4; b++) {
            int row = 32 * b + 8 * w + lr3;
            int ar = row0 + row; ar = (ar < Te ? ar : Te - 1);
            pa[b] = hidden + (size_t)(obase + ar) * F_ + slg * 8;
            pb[b] = w2b + ((size_t)e * D_ + n0 + row) * F_ + slg * 8;
        }

        f32x4 acc[4][4];
        #pragma unroll
        for (int m = 0; m < 4; m++)
            #pragma unroll
            for (int nn = 0; nn < 4; nn++) acc[m][nn] = (f32x4){0.f,0.f,0.f,0.f};

        G1_STAGE(0, 0);
        __syncthreads();
        int cur = 0;
        for (int kt = 1; kt < F_ / 64; ++kt) {
            G1_STAGE(cur ^ 1, kt * 64);
            G1_COMPUTE(cur);
            __syncthreads();
            cur ^= 1;
        }
        G1_COMPUTE(cur);

        #pragma unroll
        for (int m = 0; m < 4; m++) {
            int rbase = wr*64 + m*16 + qq * 4;
            #pragma unroll
            for (int nn = 0; nn < 4; nn++) {
                int gcol = n0 + wc*64 + nn*16 + lr;
                float bias = b2[e * D_ + gcol];
                #pragma unroll
                for (int r = 0; r < 4; r++) {
                    int lrow = rbase + r;
                    if (row0 + lrow < Te) {
                        float v = acc[m][nn][r] + bias;
                        atomicAdd(&out[(size_t)toks[lrow] * D_ + gcol], wts[lrow] * v);
                    }
                }
            }
        }
    }
}

extern "C" void kernel_launch(void* const* d_in, const int* in_sizes, int n_in,
                              void* d_out, int out_size, void* d_ws, size_t ws_size,
                              hipStream_t stream)
{
    const float* x    = (const float*)d_in[0];
    const float* keys = (const float*)d_in[1];
    const float* w1   = (const float*)d_in[2];
    const float* b1   = (const float*)d_in[3];
    const float* w2   = (const float*)d_in[4];
    const float* b2   = (const float*)d_in[5];
    const float* rw   = (const float*)d_in[6];
    const float* rb   = (const float*)d_in[7];
    float* out = (float*)d_out;

    char* wsp = (char*)d_ws;
    size_t off = 0;
    auto alloc = [&](size_t bytes) -> char* {
        char* p = wsp + off;
        off = (off + bytes + 255) & ~(size_t)255;
        return p;
    };
    int*   topi       = (int*)  alloc(NPAIR * sizeof(int));
    float* topw       = (float*)alloc(NPAIR * sizeof(float));
    int*   counts     = (int*)  alloc(E_ * sizeof(int));
    int*   offsets    = (int*)  alloc((E_ + 1) * sizeof(int));
    int*   bucket_tok = (int*)  alloc((size_t)E_ * NTOK * sizeof(int));
    float* bucket_w   = (float*)alloc((size_t)E_ * NTOK * sizeof(float));
    int*   q1         = (int*)  alloc(8 * Q1CAP * sizeof(int));
    int*   q1len      = (int*)  alloc(8 * sizeof(int));
    int*   q2         = (int*)  alloc(8 * Q2CAP * sizeof(int));
    int*   q2len      = (int*)  alloc(8 * sizeof(int));
    int*   qheads     = (int*)  alloc(16 * sizeof(int));
    unsigned short* xb     = (unsigned short*)alloc((size_t)NTOK * D_ * sizeof(unsigned short));
    unsigned short* w1b    = (unsigned short*)alloc((size_t)E_ * F_ * D_ * sizeof(unsigned short));
    unsigned short* w2b    = (unsigned short*)alloc((size_t)E_ * D_ * F_ * sizeof(unsigned short));
    unsigned short* hidden = (unsigned short*)alloc((size_t)NPAIR * F_ * sizeof(unsigned short));

    hipMemsetAsync(d_out, 0, (size_t)out_size * sizeof(float), stream);

    router_kernel<<<NTOK, 256, 0, stream>>>(x, keys, rw, rb, topi, topw, counts);
    bucket_kernel<<<NPAIR / 256, 256, 0, stream>>>(topi, topw, counts, bucket_tok, bucket_w);
    scan_kernel<<<1, 64, 0, stream>>>(counts, offsets);

    cvt_kernel<<<(NTOK * D_) / 4096, 256, 0, stream>>>(x, xb);
    cvtw_kernel<<<dim3((F_ * D_) / 4096, E_), 256, 0, stream>>>(w1, w1b, counts);
    cvtw_kernel<<<dim3((D_ * F_) / 4096, E_), 256, 0, stream>>>(w2, w2b, counts);

    plan_kernel<<<1, 512, 0, stream>>>(counts, q1, q1len, q2, q2len, qheads);

    gemm1_kernel<<<512, 256, 0, stream>>>(
        xb, w1b, b1, counts, offsets, bucket_tok, hidden, q1, q1len, qheads);
    gemm2_kernel<<<512, 256, 0, stream>>>(
        hidden, w2b, b2, counts, offsets, bucket_tok, bucket_w, out, q2, q2len, qheads);
}